// Round 20
// baseline (310.755 us; speedup 1.0000x reference)
//
#include <hip/hip_runtime.h>

// Bilateral filter, fixed shape: x[16,3,512,512] fp32, K=5, pad=2 reflect.
// sigma_color = sigma_space = 1.1; normalizations cancel in the ratio.
// w = exp2(coef2*(s+d^2)) = Ws * P(d^2); P = deg-3 Chebyshev interp of
// exp2(coef2*u) on u=[0,1] (rel err ~1e-5); Ws folded per tap class.
// Polynomial numerics VERIFIED on-device (R11/R12: absmax 0.0039 = floor).
//
// R13 (3rd submit -- prior two rounds were infra timeouts, never ran):
// R12 showed the allocator will NOT exceed the 64-VGPR/8-wave tier
// (VGPR pinned at 64 with waves_per_eu(4,4) AND named scalars; spill
// traffic persisted: FETCH 85/WRITE 147MB). Stop fighting the heuristic;
// FIT UNDER 64 BY CONSTRUCTION: stream the window rows. Only the two
// center rows persist (as d-reference + self-fold); the other 4 rows are
// loaded into ONE reusable 8-scalar buffer, tapped, and die. Static live
// peak ~44 regs (8 row + 8 centers + 16 accum + temps) vs ~70-75 for the
// up-front 6x8 window. Predict: FETCH/WRITE ~49MB each (spill gone),
// VGPR <=64 no scratch, dispatch ~38-45us.
//
// One thread = 4x2 px tile. Per row distance d from an output's center
// row, the 5 dj-blocks have classes s=(d^2)+{4,1,0,1,4}:
//   dist0 -> (4,1,skip,1,4)  [self-tap folded into accum init]
//   dist1 -> (5,2,1,2,5)
//   dist2 -> (8,5,4,5,8)
// Column reflect (verified R2-R4):
//   w0==0  : col -2 -> cv.z (col 2), col -1 -> lv.y (col 1)
//   w0==508: col 512 -> rv.x (col 510), col 513 -> cv.y (col 509)
// Row reflect: r = min(abs(r), 2*(H-1)-r).

constexpr int H_ = 512;
constexpr int W_ = 512;

// P(u) ~= exp2(coef2*u), coef2 = -log2(e)/2.42. Audit: P(0)=0.999993,
// P(0.5)=0.813330 (true 0.813335), P(1)=0.661509 (true 0.661512).
constexpr float PC0 = 0.999993f;
constexpr float PC1 = -0.412972f;
constexpr float PC2 = 0.0840929f;
constexpr float PC3 = -0.0096052f;

// Per-class coefficients K*_s = exp2(coef2*s) * PC*, s=(di-2)^2+(dj-2)^2.
#define DEFK(S, WS)                              \
    constexpr float K0_##S = (WS) * PC0;         \
    constexpr float K1_##S = (WS) * PC1;         \
    constexpr float K2_##S = (WS) * PC2;         \
    constexpr float K3_##S = (WS) * PC3;
DEFK(1, 0.6615123f)   // e^-0.413223
DEFK(2, 0.4376019f)   // ^2
DEFK(4, 0.1914962f)   // ^4
DEFK(5, 0.1266760f)   // ^5
DEFK(8, 0.0366697f)   // ^8

// One tap: w = P_s(d^2) (class-folded), accumulate num/den.
#define TAP(P, C, N, D, S)                                               \
    {                                                                    \
        float d_ = (P) - (C);                                            \
        float u_ = d_ * d_;                                              \
        float wt_ = __builtin_fmaf(                                      \
            __builtin_fmaf(__builtin_fmaf(K3_##S, u_, K2_##S), u_,       \
                           K1_##S), u_, K0_##S);                         \
        N = __builtin_fmaf(wt_, (P), N);                                 \
        D += wt_;                                                        \
    }

// One dj-block: 4 output pixels (suffix SUF in {A,B}) tap columns
// C0..C3 of the row held in scalars PFX0..PFX7, class S.
#define BLK(PFX, C0, C1, C2, C3, SUF, S)              \
    TAP(PFX##C0, cen##SUF##0, num##SUF##0, den##SUF##0, S) \
    TAP(PFX##C1, cen##SUF##1, num##SUF##1, den##SUF##1, S) \
    TAP(PFX##C2, cen##SUF##2, num##SUF##2, den##SUF##2, S) \
    TAP(PFX##C3, cen##SUF##3, num##SUF##3, den##SUF##3, S)

// Full row at distance 1 / distance 2 / distance 0 (center, dj=2 folded).
#define ROWD1(PFX, SUF)                    \
    BLK(PFX, 0, 1, 2, 3, SUF, 5)           \
    BLK(PFX, 1, 2, 3, 4, SUF, 2)           \
    BLK(PFX, 2, 3, 4, 5, SUF, 1)           \
    BLK(PFX, 3, 4, 5, 6, SUF, 2)           \
    BLK(PFX, 4, 5, 6, 7, SUF, 5)
#define ROWD2(PFX, SUF)                    \
    BLK(PFX, 0, 1, 2, 3, SUF, 8)           \
    BLK(PFX, 1, 2, 3, 4, SUF, 5)           \
    BLK(PFX, 2, 3, 4, 5, SUF, 4)           \
    BLK(PFX, 3, 4, 5, 6, SUF, 5)           \
    BLK(PFX, 4, 5, 6, 7, SUF, 8)
#define ROWD0(PFX, SUF)                    \
    BLK(PFX, 0, 1, 2, 3, SUF, 4)           \
    BLK(PFX, 1, 2, 3, 4, SUF, 1)           \
    BLK(PFX, 3, 4, 5, 6, SUF, 1)           \
    BLK(PFX, 4, 5, 6, 7, SUF, 4)

// Load one padded row (reflect) into 8 named scalars PFX0..PFX7.
#define LOADROW(PFX, RIDX)                            \
    {                                                 \
        int r_ = (RIDX);                              \
        r_ = min(abs(r_), 2 * (H_ - 1) - r_);         \
        const float* rp_ = plane + r_ * W_;           \
        float2 lv = *(const float2*)(rp_ + aL);       \
        float4 cv = *(const float4*)(rp_ + w0);       \
        float2 rv = *(const float2*)(rp_ + aR);       \
        PFX##0 = bL ? cv.z : lv.x;                    \
        PFX##1 = lv.y;                                \
        PFX##2 = cv.x; PFX##3 = cv.y;                 \
        PFX##4 = cv.z; PFX##5 = cv.w;                 \
        PFX##6 = rv.x;                                \
        PFX##7 = bR ? cv.y : rv.y;                    \
    }

__global__ __launch_bounds__(256, 4) void bilateral_kernel(
    const float* __restrict__ x,
    float* __restrict__ out,
    int nthreads)
{
    int t = blockIdx.x * 256 + threadIdx.x;
    if (t >= nthreads) return;

    int qx = t & 127;          // tile col index (4-wide tiles)
    int rg = (t >> 7) & 255;   // tile row index (2-tall tiles)
    int pl = t >> 15;          // plane (b*C + c)
    int w0 = qx << 2;
    int h0 = rg << 1;
    const float* plane = x + ((long)pl << 18);   // 512*512
    float* oplane = out + ((long)pl << 18);

    int aL = max(w0 - 2, 0);
    int aR = min(w0 + 4, W_ - 2);
    bool bL = (w0 == 0);
    bool bR = (w0 == W_ - 4);

    // Persistent: the two center rows (a = row h0, b = row h0+1).
    float a0, a1, a2, a3, a4, a5, a6, a7;
    float b0, b1, b2, b3, b4, b5, b6, b7;
    // Streamed: one reusable row buffer.
    float r0, r1, r2, r3, r4, r5, r6, r7;

    LOADROW(a, h0)
    LOADROW(b, h0 + 1)

    // Centers & accumulator init (self-tap w=1 folded in).
    float cenA0 = a2, cenA1 = a3, cenA2 = a4, cenA3 = a5;
    float cenB0 = b2, cenB1 = b3, cenB2 = b4, cenB3 = b5;
    float numA0 = cenA0, numA1 = cenA1, numA2 = cenA2, numA3 = cenA3;
    float numB0 = cenB0, numB1 = cenB1, numB2 = cenB2, numB3 = cenB3;
    float denA0 = 1.f, denA1 = 1.f, denA2 = 1.f, denA3 = 1.f;
    float denB0 = 1.f, denB1 = 1.f, denB2 = 1.f, denB3 = 1.f;

    // Center rows tap each other & themselves, then their extras die.
    ROWD0(a, A)     // row h0  -> out0 (dist 0, self-fold)
    ROWD1(a, B)     // row h0  -> out1 (dist 1)
    ROWD1(b, A)     // row h0+1 -> out0 (dist 1)
    ROWD0(b, B)     // row h0+1 -> out1 (dist 0, self-fold)

    // Stream the remaining 4 rows through r (load -> tap -> dead).
    LOADROW(r, h0 - 1)
    ROWD1(r, A)     // dist 1 to out0
    ROWD2(r, B)     // dist 2 to out1
    LOADROW(r, h0 - 2)
    ROWD2(r, A)     // dist 2 to out0 (not in out1 window)
    LOADROW(r, h0 + 2)
    ROWD2(r, A)     // dist 2 to out0
    ROWD1(r, B)     // dist 1 to out1
    LOADROW(r, h0 + 3)
    ROWD2(r, B)     // dist 2 to out1 (not in out0 window)

    float4 o;
    o.x = numA0 * __builtin_amdgcn_rcpf(denA0);
    o.y = numA1 * __builtin_amdgcn_rcpf(denA1);
    o.z = numA2 * __builtin_amdgcn_rcpf(denA2);
    o.w = numA3 * __builtin_amdgcn_rcpf(denA3);
    *(float4*)(oplane + h0 * W_ + w0) = o;
    o.x = numB0 * __builtin_amdgcn_rcpf(denB0);
    o.y = numB1 * __builtin_amdgcn_rcpf(denB1);
    o.z = numB2 * __builtin_amdgcn_rcpf(denB2);
    o.w = numB3 * __builtin_amdgcn_rcpf(denB3);
    *(float4*)(oplane + (h0 + 1) * W_ + w0) = o;
}

extern "C" void kernel_launch(void* const* d_in, const int* in_sizes, int n_in,
                              void* d_out, int out_size, void* d_ws, size_t ws_size,
                              hipStream_t stream)
{
    const float* x = (const float*)d_in[0];
    float* out = (float*)d_out;
    int nthreads = in_sizes[0] >> 3;         // 8 px per thread (4x2 tile)
    int blocks = (nthreads + 255) / 256;
    bilateral_kernel<<<blocks, 256, 0, stream>>>(x, out, nthreads);
}

// Round 23
// 127.752 us; speedup vs baseline: 2.4325x; 2.4325x over previous
//
#include <hip/hip_runtime.h>

// Bilateral filter, fixed shape: x[16,3,512,512] fp32, K=5, pad=2 reflect.
// sigma_color = sigma_space = 1.1; normalizations cancel in the ratio.
// w = exp2(coef2*d^2 + cs), coef2 = -log2(e)/2.42, cs = coef2*s.
//
// R14 (3rd submit -- prior two rounds were infra timeouts, never ran):
// back to the ONLY verified-good structure (R6: VGPR 48, no spill,
// 53.8us, VALUBusy 72%), minus 1 VALU/tap via two exact algebraic folds:
//  (a) window prescaled by ALPHA=sqrt(-coef2) at load (48 muls, replaces
//      raw window -> liveness unchanged). arg = cs - d'^2 where d'=p'-c'
//      = ONE fma with neg modifier: v_fma_f32(-d', d', cs). The per-tap
//      mul is gone.
//  (b) accumulate nd = sum(w*d') instead of num: out = (c' + nd/den)*INVA.
//      num-fma -> fmac(w,d'); center tap folds exactly (d'=0).
// Per tap: sub, fma, exp, fmac, add = 4 VALU + 1 trans (~16 cyc vs 19
// measured). Constants: 5 cs + INVA in SGPRs (fma reads <=1 SGPR, no
// VGPR copies -- the poly path's fatal flaw avoided).
// Spill ledger: R10-R13 all spilled (FETCH/WRITE up to 336/602MB) from
// live sets ~70+; this kernel's live set = R6 + 1.
// Predict: FETCH/WRITE ~49MB, VGPR 48-56, dispatch ~47-50us.
//
// One thread = 4x2 px tile; 6x8 prescaled f32 register window, direct
// constant indexing only (R0/R6-proven register-resident pattern).
// Column reflect (verified R2-R4):
//   w0==0  : col -2 -> cv.z (col 2), col -1 -> lv.y (col 1)
//   w0==508: col 512 -> rv.x (col 510), col 513 -> cv.y (col 509)
// Row reflect: r = min(abs(r), 2*(H-1)-r).

constexpr int H_ = 512;
constexpr int W_ = 512;

constexpr float COEF2 = -0.59615498f;   // -log2(e)/(2*1.21)
constexpr float ALPHA = 0.77211078f;    // sqrt(-COEF2)
constexpr float INVA  = 1.29514928f;    // 1/ALPHA

// cs = COEF2 * s for s in {1,2,4,5,8} (compile-time).
__device__ constexpr float CS_of(int s) { return COEF2 * (float)s; }

// One tap: d' = p' - c'; arg = cs - d'^2 (single fma, neg modifier);
// w = exp2(arg); nd += w*d'; den += w.
#define TAP(P, C, ND, DEN, S)                                            \
    {                                                                    \
        float d_ = (P) - (C);                                            \
        float arg_ = __builtin_fmaf(-d_, d_, CS_of(S));                  \
        float w_ = __builtin_amdgcn_exp2f(arg_);                         \
        ND = __builtin_fmaf(w_, d_, ND);                                 \
        DEN += w_;                                                       \
    }

__global__ __launch_bounds__(256, 4) void bilateral_kernel(
    const float* __restrict__ x,
    float* __restrict__ out,
    int nthreads)
{
    int t = blockIdx.x * 256 + threadIdx.x;
    if (t >= nthreads) return;

    int qx = t & 127;          // tile col index (4-wide tiles)
    int rg = (t >> 7) & 255;   // tile row index (2-tall tiles)
    int pl = t >> 15;          // plane (b*C + c)
    int w0 = qx << 2;
    int h0 = rg << 1;
    const float* plane = x + ((long)pl << 18);   // 512*512
    float* oplane = out + ((long)pl << 18);

    int aL = max(w0 - 2, 0);
    int aR = min(w0 + 4, W_ - 2);
    bool bL = (w0 == 0);
    bool bR = (w0 == W_ - 4);

    // 6x8 window PRESCALED by ALPHA: rows h0-2..h0+3, cols w0-2..w0+5.
    // Direct constant indexing only -> register-resident (R0/R6 proven).
    float Wn[6][8];
#pragma unroll
    for (int k = 0; k < 6; ++k) {
        int r = h0 + k - 2;
        r = min(abs(r), 2 * (H_ - 1) - r);
        const float* rp = plane + r * W_;
        float2 lv = *(const float2*)(rp + aL);
        float4 cv = *(const float4*)(rp + w0);
        float2 rv = *(const float2*)(rp + aR);
        Wn[k][0] = ALPHA * (bL ? cv.z : lv.x);   // reflect col -2 -> +2
        Wn[k][1] = ALPHA * lv.y;                 // col -1 (== col 1 if bL)
        Wn[k][2] = ALPHA * cv.x;
        Wn[k][3] = ALPHA * cv.y;
        Wn[k][4] = ALPHA * cv.z;
        Wn[k][5] = ALPHA * cv.w;
        Wn[k][6] = ALPHA * rv.x;                 // col +4 (== 510 if bR)
        Wn[k][7] = ALPHA * (bR ? cv.y : rv.y);   // reflect col 513 -> 509
    }

#pragma unroll
    for (int oi = 0; oi < 2; ++oi) {
        float c0 = Wn[oi + 2][2], c1 = Wn[oi + 2][3];
        float c2 = Wn[oi + 2][4], c3 = Wn[oi + 2][5];
        // Center tap folded exactly: w=1 -> den=1, nd += 0.
        float nd0 = 0.f, nd1 = 0.f, nd2 = 0.f, nd3 = 0.f;
        float den0 = 1.f, den1 = 1.f, den2 = 1.f, den3 = 1.f;
#pragma unroll
        for (int di = 0; di < 5; ++di) {
#pragma unroll
            for (int dj = 0; dj < 5; ++dj) {
                if (di == 2 && dj == 2) continue;   // center handled above
                const int s = (di - 2) * (di - 2) + (dj - 2) * (dj - 2);
                TAP(Wn[oi + di][dj + 0], c0, nd0, den0, s)
                TAP(Wn[oi + di][dj + 1], c1, nd1, den1, s)
                TAP(Wn[oi + di][dj + 2], c2, nd2, den2, s)
                TAP(Wn[oi + di][dj + 3], c3, nd3, den3, s)
            }
        }
        // out = (c' + nd/den) * INVA   (unscale once per pixel)
        float4 o;
        o.x = (c0 + nd0 * __builtin_amdgcn_rcpf(den0)) * INVA;
        o.y = (c1 + nd1 * __builtin_amdgcn_rcpf(den1)) * INVA;
        o.z = (c2 + nd2 * __builtin_amdgcn_rcpf(den2)) * INVA;
        o.w = (c3 + nd3 * __builtin_amdgcn_rcpf(den3)) * INVA;
        *(float4*)(oplane + (h0 + oi) * W_ + w0) = o;
    }
}

extern "C" void kernel_launch(void* const* d_in, const int* in_sizes, int n_in,
                              void* d_out, int out_size, void* d_ws, size_t ws_size,
                              hipStream_t stream)
{
    const float* x = (const float*)d_in[0];
    float* out = (float*)d_out;
    int nthreads = in_sizes[0] >> 3;         // 8 px per thread (4x2 tile)
    int blocks = (nthreads + 255) / 256;
    bilateral_kernel<<<blocks, 256, 0, stream>>>(x, out, nthreads);
}